// Round 3
// baseline (1542.918 us; speedup 1.0000x reference)
//
#include <hip/hip_runtime.h>
#include <stdint.h>

#define NPTS 2048
#define SOUT 512
#define NB   2
#define T1   256
#define PPT  (NPTS / T1)   // 8 points per thread
#define NW   (T1 / 64)     // 4 waves
#define T2   64

// ---------------- Kernel 1: farthest point sampling (bit-exact vs numpy) -----
// One block per batch. 8 points/lane in registers; xyz in LDS for centroid
// gather. Per round: no-FMA distance update -> __shfl_down wave argmax
// (value max, min index on ties = numpy first-occurrence) -> 4 wave-leader
// slots in LDS (parity double-buffered, one barrier/round); leaders pre-fetch
// candidate coords so the post-barrier path is slot reads only.
__global__ __launch_bounds__(T1, 1) void fps_kernel(const float* __restrict__ xyz,
                                                    float* __restrict__ new_xyz,
                                                    int far0, int far1) {
    __shared__ float4 sxyz[NPTS];          // 32 KB
    __shared__ float4 slot[2][NW][2];      // {val, idx, cx, cy} {cz, -,-,-}
    const int b   = blockIdx.x;
    const int tid = threadIdx.x;
    const int lane = tid & 63;
    const int wv   = tid >> 6;
    const float* xb = xyz + (size_t)b * NPTS * 3;
    for (int i = tid; i < NPTS; i += T1)
        sxyz[i] = make_float4(xb[i*3+0], xb[i*3+1], xb[i*3+2], 0.0f);
    __syncthreads();

    float px[PPT], py[PPT], pz[PPT], dd[PPT];
#pragma unroll
    for (int k = 0; k < PPT; ++k) {
        float4 p = sxyz[tid + k * T1];
        px[k] = p.x; py[k] = p.y; pz[k] = p.z; dd[k] = 1e10f;
    }
    int far = (b == 0) ? far0 : far1;
    float4 c0 = sxyz[far];
    float cx = c0.x, cy = c0.y, cz = c0.z;
    float* ob = new_xyz + (size_t)b * SOUT * 3;

    for (int s = 0; s < SOUT; ++s) {
        if (tid == 0) { ob[s*3+0] = cx; ob[s*3+1] = cy; ob[s*3+2] = cz; }
        if (s == SOUT - 1) break;
        // update distances (no FMA: must match numpy rounding exactly)
        float bv = -1.0f; int bi = 0;
#pragma unroll
        for (int k = 0; k < PPT; ++k) {
            float dx = __fsub_rn(px[k], cx);
            float dy = __fsub_rn(py[k], cy);
            float dz = __fsub_rn(pz[k], cz);
            float d2 = __fadd_rn(__fadd_rn(__fmul_rn(dx,dx), __fmul_rn(dy,dy)), __fmul_rn(dz,dz));
            d2 = fminf(dd[k], d2);
            dd[k] = d2;
            if (d2 > bv) { bv = d2; bi = tid + k * T1; }   // strict >: keeps smallest idx
        }
        // wave argmax via shuffles: value max, min index among value-ties
        // (lexicographic total-order max -> tree reduction is exact)
#pragma unroll
        for (int off = 32; off > 0; off >>= 1) {
            float ov = __shfl_down(bv, off);
            int   oi = __shfl_down(bi, off);
            if (ov > bv || (ov == bv && oi < bi)) { bv = ov; bi = oi; }
        }
        const int par = s & 1;
        if (lane == 0) {
            float4 cc = sxyz[bi];
            slot[par][wv][0] = make_float4(bv, __int_as_float(bi), cc.x, cc.y);
            slot[par][wv][1] = make_float4(cc.z, 0.f, 0.f, 0.f);
        }
        __syncthreads();
        float4 a = slot[par][0][0];
        float bvv = a.x; int bii = __float_as_int(a.y);
        float bx = a.z, by = a.w, bz = slot[par][0][1].x;
#pragma unroll
        for (int w = 1; w < NW; ++w) {
            float4 aw = slot[par][w][0];
            float czw = slot[par][w][1].x;
            int  iw  = __float_as_int(aw.y);
            bool take = (aw.x > bvv) || ((aw.x == bvv) && (iw < bii));
            if (take) { bvv = aw.x; bii = iw; bx = aw.z; by = aw.w; bz = czw; }
        }
        cx = bx; cy = by; cz = bz;
    }
}

// ---------------- Kernel 2: radius group + MLP(16->32->32->64) + maxpool -----
// One wave per query (grid = B*S blocks of 64). Padding with duplicated first
// neighbor == reference semantics and is a no-op under max.
__global__ __launch_bounds__(T2, 1) void group_mlp_kernel(
        const float* __restrict__ xyz,  const float* __restrict__ points,
        const float* __restrict__ w1,   const float* __restrict__ b1,
        const float* __restrict__ w2,   const float* __restrict__ b2,
        const float* __restrict__ w3,   const float* __restrict__ b3,
        const float* __restrict__ new_xyz, float* __restrict__ new_points) {
    __shared__ float sw1[32*16];
    __shared__ float sw2[32*32];
    __shared__ float sw3[64*32];
    __shared__ float sb1[32], sb2[32], sb3[64];
    __shared__ int   sidx[NPTS];
    __shared__ float sout[64*65];          // stride 65: conflict-free transpose
    const int lane = threadIdx.x;
    for (int i = lane; i <  512; i += T2) sw1[i] = w1[i];
    for (int i = lane; i < 1024; i += T2) sw2[i] = w2[i];
    for (int i = lane; i < 2048; i += T2) sw3[i] = w3[i];
    if (lane < 32) { sb1[lane] = b1[lane]; sb2[lane] = b2[lane]; }
    sb3[lane] = b3[lane];

    const int q = blockIdx.x;
    const int b = q >> 9;
    const int s = q & (SOUT - 1);
    const float qx = new_xyz[q*3+0], qy = new_xyz[q*3+1], qz = new_xyz[q*3+2];
    const float qs = __fadd_rn(__fadd_rn(__fmul_rn(qx,qx), __fmul_rn(qy,qy)), __fmul_rn(qz,qz));
    const float* xb = xyz    + (size_t)b * NPTS * 3;
    const float* pb = points + (size_t)b * 13 * NPTS;
    __syncthreads();

    // scan all N points, ballot-compact within-radius indices (ascending)
    int cnt = 0;
    for (int r = 0; r < NPTS / T2; ++r) {
        int n = r * T2 + lane;
        float x = xb[n*3+0], y = xb[n*3+1], z = xb[n*3+2];
        float pn = __fadd_rn(__fadd_rn(__fmul_rn(x,x), __fmul_rn(y,y)), __fmul_rn(z,z));
        float dt = __fadd_rn(__fadd_rn(__fmul_rn(qx,x), __fmul_rn(qy,y)), __fmul_rn(qz,z));
        float sqr = __fsub_rn(__fadd_rn(qs, pn), __fmul_rn(2.0f, dt));
        bool sel = !(sqr > 0.04f);                    // keep iff sqr <= r^2 (f32)
        unsigned long long m = __ballot(sel);
        if (sel) sidx[cnt + __popcll(m & ((1ull << lane) - 1ull))] = n;
        cnt += (int)__popcll(m);
    }
    __syncthreads();
    const int K = cnt;                                 // >= 1 (query is its own neighbor)
    const int nfirst = sidx[0];

    float om[64];
#pragma unroll
    for (int o = 0; o < 64; ++o) om[o] = -3.0e38f;

    for (int t = 0; t < K; t += T2) {
        int m = t + lane;
        int n = (m < K) ? sidx[m] : nfirst;            // pad = first neighbor (= reference)
        float f[16];
        f[0] = xb[n*3+0] - qx;
        f[1] = xb[n*3+1] - qy;
        f[2] = xb[n*3+2] - qz;
#pragma unroll
        for (int c = 0; c < 13; ++c) f[3+c] = pb[c*NPTS + n];
        float h1[32];
#pragma unroll
        for (int o = 0; o < 32; ++o) {
            float acc = sb1[o];
            const float4* wr = (const float4*)(sw1 + o*16);
#pragma unroll
            for (int c4 = 0; c4 < 4; ++c4) {
                float4 w = wr[c4];
                acc = fmaf(f[c4*4+0], w.x, acc);
                acc = fmaf(f[c4*4+1], w.y, acc);
                acc = fmaf(f[c4*4+2], w.z, acc);
                acc = fmaf(f[c4*4+3], w.w, acc);
            }
            h1[o] = fmaxf(acc, 0.0f);
        }
        float h2[32];
#pragma unroll
        for (int o = 0; o < 32; ++o) {
            float acc = sb2[o];
            const float4* wr = (const float4*)(sw2 + o*32);
#pragma unroll
            for (int c4 = 0; c4 < 8; ++c4) {
                float4 w = wr[c4];
                acc = fmaf(h1[c4*4+0], w.x, acc);
                acc = fmaf(h1[c4*4+1], w.y, acc);
                acc = fmaf(h1[c4*4+2], w.z, acc);
                acc = fmaf(h1[c4*4+3], w.w, acc);
            }
            h2[o] = fmaxf(acc, 0.0f);
        }
#pragma unroll
        for (int o = 0; o < 64; ++o) {
            float acc = sb3[o];
            const float4* wr = (const float4*)(sw3 + o*32);
#pragma unroll
            for (int c4 = 0; c4 < 8; ++c4) {
                float4 w = wr[c4];
                acc = fmaf(h2[c4*4+0], w.x, acc);
                acc = fmaf(h2[c4*4+1], w.y, acc);
                acc = fmaf(h2[c4*4+2], w.z, acc);
                acc = fmaf(h2[c4*4+3], w.w, acc);
            }
            om[o] = fmaxf(om[o], acc);
        }
    }
    // cross-lane per-channel max via LDS transpose (stride 65 -> conflict-free)
#pragma unroll
    for (int o = 0; o < 64; ++o) sout[lane*65 + o] = om[o];
    __syncthreads();
    float mx = sout[lane];
#pragma unroll
    for (int l = 1; l < 64; ++l) mx = fmaxf(mx, sout[l*65 + lane]);
    new_points[((size_t)b * 64 + lane) * SOUT + s] = mx;   // (B, 64, S)
}

// ---------------- host: threefry2x32 (JAX key(42) randint seed) --------------
static inline uint32_t rotl32(uint32_t x, int r) { return (x << r) | (x >> (32 - r)); }
static void threefry2x32_host(uint32_t k0, uint32_t k1, uint32_t& x0, uint32_t& x1) {
    const int R[2][4] = {{13,15,26,6},{17,29,16,24}};
    uint32_t ks[3] = {k0, k1, k0 ^ k1 ^ 0x1BD11BDAu};
    x0 += ks[0]; x1 += ks[1];
    for (int i = 0; i < 5; ++i) {
        for (int j = 0; j < 4; ++j) { x0 += x1; x1 = rotl32(x1, R[i & 1][j]); x1 ^= x0; }
        x0 += ks[(i + 1) % 3];
        x1 += ks[(i + 2) % 3] + (uint32_t)(i + 1);
    }
}

extern "C" void kernel_launch(void* const* d_in, const int* in_sizes, int n_in,
                              void* d_out, int out_size, void* d_ws, size_t ws_size,
                              hipStream_t stream) {
    const float* xyz    = (const float*)d_in[0];
    const float* points = (const float*)d_in[1];
    const float* w1 = (const float*)d_in[2];
    const float* b1 = (const float*)d_in[3];
    const float* w2 = (const float*)d_in[4];
    const float* b2 = (const float*)d_in[5];
    const float* w3 = (const float*)d_in[6];
    const float* b3 = (const float*)d_in[7];
    float* out        = (float*)d_out;
    float* new_xyz    = out;                      // (B, S, 3)
    float* new_points = out + NB * SOUT * 3;      // (B, 64, S)

    // jax.random.randint(key(42), (2,), 0, 2048), modern JAX
    // (jax_threefry_partitionable=True, default since 0.5.0):
    //   _randint SPLITS the key first (missed in rounds 0-2!):
    //     k1, k2 = split(key); lower_bits = random_bits(k2, 32, (2,))
    //   span = 2048 = 2^11 -> multiplier = (2^16 % 2048)^2 % 2048 = 0,
    //   so result = lower_bits & 2047 (higher_bits/k1 unused).
    //   foldlike split: k2 = full output pair of threefry((0,42), (0,1)).
    //   partitionable random_bits(32): elem i = xor of threefry(k2, (0,i)).
    // Fallback if this still mismatches (legacy, partitionable=False):
    //   split: counts [0,1,2,3] -> blocks (0,2),(1,3); k2 = (y1_0, y1_1);
    //   bits: single block threefry(k2, (0,1)) -> (b0, b1) used directly.
    uint32_t k2a = 0, k2b = 1; threefry2x32_host(0u, 42u, k2a, k2b);  // k2 = split(key)[1]
    uint32_t u0 = 0, u1 = 0;  threefry2x32_host(k2a, k2b, u0, u1);    // elem 0: ctr (0,0)
    uint32_t v0 = 0, v1 = 1;  threefry2x32_host(k2a, k2b, v0, v1);    // elem 1: ctr (0,1)
    int far0 = (int)((u0 ^ u1) & (NPTS - 1));
    int far1 = (int)((v0 ^ v1) & (NPTS - 1));

    hipLaunchKernelGGL(fps_kernel, dim3(NB), dim3(T1), 0, stream,
                       xyz, new_xyz, far0, far1);
    hipLaunchKernelGGL(group_mlp_kernel, dim3(NB * SOUT), dim3(T2), 0, stream,
                       xyz, points, w1, b1, w2, b2, w3, b3, new_xyz, new_points);
}

// Round 4
// 440.920 us; speedup vs baseline: 3.4993x; 3.4993x over previous
//
#include <hip/hip_runtime.h>
#include <stdint.h>

#define NPTS 2048
#define SOUT 512
#define NB   2
#define T1   256
#define PPT  (NPTS / T1)   // 8 points per thread (k-major: lane owns tid*8..tid*8+7)
#define NW   (T1 / 64)     // 4 waves
#define T2   64

// ---- DPP wave64 max-reduce (nonneg values; bound_ctrl zero-fill is safe) ----
// Canonical gfx9 sequence: row_shr 1/2/4/8, row_bcast15 (rows 1,3),
// row_bcast31 (rows 2,3); total in lane 63 -> readlane broadcast.
__device__ __forceinline__ float wave_allmax_f32(float v) {
    int x = __float_as_int(v); int t;
    t = __builtin_amdgcn_update_dpp(x, x, 0x111, 0xF, 0xF, true); v = fmaxf(v, __int_as_float(t)); x = __float_as_int(v);
    t = __builtin_amdgcn_update_dpp(x, x, 0x112, 0xF, 0xF, true); v = fmaxf(v, __int_as_float(t)); x = __float_as_int(v);
    t = __builtin_amdgcn_update_dpp(x, x, 0x114, 0xF, 0xF, true); v = fmaxf(v, __int_as_float(t)); x = __float_as_int(v);
    t = __builtin_amdgcn_update_dpp(x, x, 0x118, 0xF, 0xF, true); v = fmaxf(v, __int_as_float(t)); x = __float_as_int(v);
    t = __builtin_amdgcn_update_dpp(x, x, 0x142, 0xA, 0xF, true); v = fmaxf(v, __int_as_float(t)); x = __float_as_int(v);
    t = __builtin_amdgcn_update_dpp(x, x, 0x143, 0xC, 0xF, true); v = fmaxf(v, __int_as_float(t)); x = __float_as_int(v);
    return __int_as_float(__builtin_amdgcn_readlane(x, 63));
}

// ---------------- Kernel 1: farthest point sampling (bit-exact vs numpy) -----
// One block per batch, 4 waves. k-major point ownership so that lane order ==
// global index order (ballot-ctz == numpy first-occurrence argmax on ties).
// No global ops inside the round loop (coords buffered in LDS) -> the
// pre-barrier waitcnt drain is lgkm-only and cheap.
__global__ __launch_bounds__(T1, 1) void fps_kernel(const float* __restrict__ xyz,
                                                    float* __restrict__ new_xyz,
                                                    int far0, int far1) {
    __shared__ float4 sxyz[NPTS];          // 32 KB
    __shared__ float4 slot[2][NW][2];      // {val, idx, cx, cy} {cz,-,-,-}
    __shared__ float  scf[SOUT * 3];       // centroid coords, written once at end
    const int b    = blockIdx.x;
    const int tid  = threadIdx.x;
    const int lane = tid & 63;
    const int wv   = tid >> 6;
    const float* xb = xyz + (size_t)b * NPTS * 3;
    for (int i = tid; i < NPTS; i += T1)
        sxyz[i] = make_float4(xb[i*3+0], xb[i*3+1], xb[i*3+2], 0.0f);
    __syncthreads();

    float px[PPT], py[PPT], pz[PPT], dd[PPT];
    const int gbase = tid * PPT;           // k-major: lane owns [tid*8, tid*8+8)
#pragma unroll
    for (int k = 0; k < PPT; ++k) {
        float4 p = sxyz[gbase + k];
        px[k] = p.x; py[k] = p.y; pz[k] = p.z; dd[k] = 1e10f;
    }
    int far = (b == 0) ? far0 : far1;
    float4 c0 = sxyz[far];
    float cx = c0.x, cy = c0.y, cz = c0.z;

    for (int s = 0; s < SOUT; ++s) {
        if (tid == 0) { scf[s*3+0] = cx; scf[s*3+1] = cy; scf[s*3+2] = cz; }
        if (s == SOUT - 1) break;
        // distance update (no FMA: must match numpy rounding bit-exactly)
        float bv = -1.0f; int bi = 0;
#pragma unroll
        for (int k = 0; k < PPT; ++k) {
            float dx = __fsub_rn(px[k], cx);
            float dy = __fsub_rn(py[k], cy);
            float dz = __fsub_rn(pz[k], cz);
            float d2 = __fadd_rn(__fadd_rn(__fmul_rn(dx,dx), __fmul_rn(dy,dy)), __fmul_rn(dz,dz));
            d2 = fminf(dd[k], d2);
            dd[k] = d2;
            if (d2 > bv) { bv = d2; bi = gbase + k; }  // strict >: keeps smallest idx
        }
        // wave argmax: DPP value-max, then lowest lane among ties (= lowest
        // global index, since lane order == index order under k-major).
        float wmax = wave_allmax_f32(bv);
        unsigned long long msk = __ballot(bv == wmax);
        int l0  = (int)__builtin_ctzll(msk);
        int wbi = __builtin_amdgcn_readlane(bi, l0);
        const int par = s & 1;
        if (lane == 0) {
            float4 cc = sxyz[wbi];
            slot[par][wv][0] = make_float4(wmax, __int_as_float(wbi), cc.x, cc.y);
            slot[par][wv][1] = make_float4(cc.z, 0.f, 0.f, 0.f);
        }
        __syncthreads();
        float4 a = slot[par][0][0];
        float bvv = a.x; int bii = __float_as_int(a.y);
        float bx = a.z, by = a.w, bz = slot[par][0][1].x;
#pragma unroll
        for (int w = 1; w < NW; ++w) {
            float4 aw = slot[par][w][0];
            float czw = slot[par][w][1].x;
            int  iw  = __float_as_int(aw.y);
            bool take = (aw.x > bvv) || ((aw.x == bvv) && (iw < bii));
            if (take) { bvv = aw.x; bii = iw; bx = aw.z; by = aw.w; bz = czw; }
        }
        cx = bx; cy = by; cz = bz;
    }
    __syncthreads();
    float* ob = new_xyz + (size_t)b * SOUT * 3;
    for (int i = tid; i < SOUT * 3; i += T1) ob[i] = scf[i];   // coalesced epilogue
}

// ---------------- Kernel 2: radius group + MLP(16->32->32->64) + maxpool -----
// One wave per query. Layers 1-2: lane = neighbor (h1/h2 in registers, weights
// broadcast from LDS). Layer 3: transpose via LDS (stride 36, 16B-aligned) ->
// lane = output channel, w3 row in 32 registers (loaded once from global),
// single running-max VGPR. No per-lane array >32 -> no scratch spills.
__global__ __launch_bounds__(T2, 1) void group_mlp_kernel(
        const float* __restrict__ xyz,  const float* __restrict__ points,
        const float* __restrict__ w1,   const float* __restrict__ b1,
        const float* __restrict__ w2,   const float* __restrict__ b2,
        const float* __restrict__ w3,   const float* __restrict__ b3,
        const float* __restrict__ new_xyz, float* __restrict__ new_points) {
    __shared__ float sw1[32*16];
    __shared__ float sw2[32*32];
    __shared__ float sb1[32], sb2[32];
    __shared__ int   sidx[NPTS];           // 8 KB
    __shared__ float sh2[64*36];           // 9 KB, stride 36 (16B-aligned rows)
    const int lane = threadIdx.x;
    for (int i = lane; i <  512; i += T2) sw1[i] = w1[i];
    for (int i = lane; i < 1024; i += T2) sw2[i] = w2[i];
    if (lane < 32) { sb1[lane] = b1[lane]; sb2[lane] = b2[lane]; }

    // per-lane w3 row (64x32 row-major -> lane o reads w3[o*32..o*32+31])
    float wf3[32];
    {
        const float4* w3v = (const float4*)(w3 + lane * 32);
#pragma unroll
        for (int j = 0; j < 8; ++j) {
            float4 w = w3v[j];
            wf3[j*4+0] = w.x; wf3[j*4+1] = w.y; wf3[j*4+2] = w.z; wf3[j*4+3] = w.w;
        }
    }
    const float rb3 = b3[lane];

    const int q = blockIdx.x;
    const int b = q >> 9;
    const int s = q & (SOUT - 1);
    const float qx = new_xyz[q*3+0], qy = new_xyz[q*3+1], qz = new_xyz[q*3+2];
    const float qs = __fadd_rn(__fadd_rn(__fmul_rn(qx,qx), __fmul_rn(qy,qy)), __fmul_rn(qz,qz));
    const float* xb = xyz    + (size_t)b * NPTS * 3;
    const float* pb = points + (size_t)b * 13 * NPTS;
    __syncthreads();

    // scan all N points, ballot-compact within-radius indices (ascending)
    int cnt = 0;
    for (int r = 0; r < NPTS / T2; ++r) {
        int n = r * T2 + lane;
        float x = xb[n*3+0], y = xb[n*3+1], z = xb[n*3+2];
        float pn = __fadd_rn(__fadd_rn(__fmul_rn(x,x), __fmul_rn(y,y)), __fmul_rn(z,z));
        float dt = __fadd_rn(__fadd_rn(__fmul_rn(qx,x), __fmul_rn(qy,y)), __fmul_rn(qz,z));
        float sqr = __fsub_rn(__fadd_rn(qs, pn), __fmul_rn(2.0f, dt));
        bool sel = !(sqr > 0.04f);                    // keep iff sqr <= r^2 (f32)
        unsigned long long m = __ballot(sel);
        if (sel) sidx[cnt + __popcll(m & ((1ull << lane) - 1ull))] = n;
        cnt += (int)__popcll(m);
    }
    __syncthreads();
    const int K = cnt;                                 // >= 1 (query is its own neighbor)
    const int nfirst = sidx[0];

    float mx = -3.0e38f;                               // lane's output channel max

    for (int t = 0; t < K; t += T2) {
        int m = t + lane;
        int n = (m < K) ? sidx[m] : nfirst;            // pad = first neighbor (= reference)
        float f[16];
        f[0] = xb[n*3+0] - qx;
        f[1] = xb[n*3+1] - qy;
        f[2] = xb[n*3+2] - qz;
#pragma unroll
        for (int c = 0; c < 13; ++c) f[3+c] = pb[c*NPTS + n];
        float h1[32];
#pragma unroll
        for (int o = 0; o < 32; ++o) {
            float acc = sb1[o];
            const float4* wr = (const float4*)(sw1 + o*16);
#pragma unroll
            for (int c4 = 0; c4 < 4; ++c4) {
                float4 w = wr[c4];
                acc = fmaf(f[c4*4+0], w.x, acc);
                acc = fmaf(f[c4*4+1], w.y, acc);
                acc = fmaf(f[c4*4+2], w.z, acc);
                acc = fmaf(f[c4*4+3], w.w, acc);
            }
            h1[o] = fmaxf(acc, 0.0f);
        }
        float h2[32];
#pragma unroll
        for (int o = 0; o < 32; ++o) {
            float acc = sb2[o];
            const float4* wr = (const float4*)(sw2 + o*32);
#pragma unroll
            for (int c4 = 0; c4 < 8; ++c4) {
                float4 w = wr[c4];
                acc = fmaf(h1[c4*4+0], w.x, acc);
                acc = fmaf(h1[c4*4+1], w.y, acc);
                acc = fmaf(h1[c4*4+2], w.z, acc);
                acc = fmaf(h1[c4*4+3], w.w, acc);
            }
            h2[o] = fmaxf(acc, 0.0f);
        }
        // stage h2 (lane = neighbor row), then lane = output channel
        {
            float4* row = (float4*)(sh2 + lane * 36);
#pragma unroll
            for (int c4 = 0; c4 < 8; ++c4)
                row[c4] = make_float4(h2[c4*4+0], h2[c4*4+1], h2[c4*4+2], h2[c4*4+3]);
        }
        __syncthreads();
#pragma unroll 4
        for (int n2 = 0; n2 < T2; ++n2) {              // dup pads are no-ops under max
            const float4* hr = (const float4*)(sh2 + n2 * 36);
            float acc = rb3;
#pragma unroll
            for (int c4 = 0; c4 < 8; ++c4) {
                float4 h = hr[c4];                     // broadcast read
                acc = fmaf(h.x, wf3[c4*4+0], acc);
                acc = fmaf(h.y, wf3[c4*4+1], acc);
                acc = fmaf(h.z, wf3[c4*4+2], acc);
                acc = fmaf(h.w, wf3[c4*4+3], acc);
            }
            mx = fmaxf(mx, acc);
        }
        __syncthreads();                               // WAR before next chunk's writes
    }
    new_points[((size_t)b * 64 + lane) * SOUT + s] = mx;   // (B, 64, S)
}

// ---------------- host: threefry2x32 (JAX key(42) randint seed) --------------
static inline uint32_t rotl32(uint32_t x, int r) { return (x << r) | (x >> (32 - r)); }
static void threefry2x32_host(uint32_t k0, uint32_t k1, uint32_t& x0, uint32_t& x1) {
    const int R[2][4] = {{13,15,26,6},{17,29,16,24}};
    uint32_t ks[3] = {k0, k1, k0 ^ k1 ^ 0x1BD11BDAu};
    x0 += ks[0]; x1 += ks[1];
    for (int i = 0; i < 5; ++i) {
        for (int j = 0; j < 4; ++j) { x0 += x1; x1 = rotl32(x1, R[i & 1][j]); x1 ^= x0; }
        x0 += ks[(i + 1) % 3];
        x1 += ks[(i + 2) % 3] + (uint32_t)(i + 1);
    }
}

extern "C" void kernel_launch(void* const* d_in, const int* in_sizes, int n_in,
                              void* d_out, int out_size, void* d_ws, size_t ws_size,
                              hipStream_t stream) {
    const float* xyz    = (const float*)d_in[0];
    const float* points = (const float*)d_in[1];
    const float* w1 = (const float*)d_in[2];
    const float* b1 = (const float*)d_in[3];
    const float* w2 = (const float*)d_in[4];
    const float* b2 = (const float*)d_in[5];
    const float* w3 = (const float*)d_in[6];
    const float* b3 = (const float*)d_in[7];
    float* out        = (float*)d_out;
    float* new_xyz    = out;                      // (B, S, 3)
    float* new_points = out + NB * SOUT * 3;      // (B, 64, S)

    // jax.random.randint(key(42), (2,), 0, 2048), modern JAX
    // (jax_threefry_partitionable=True): _randint splits the key first:
    //   k1, k2 = split(key); result = random_bits(k2, 32, (2,)) & 2047
    // foldlike split: k2 = threefry((0,42),(0,1)) full pair.
    // partitionable bits: elem i = xor-halves of threefry(k2, (0,i)).
    // (VERIFIED passing in round 3 — do not change.)
    uint32_t k2a = 0, k2b = 1; threefry2x32_host(0u, 42u, k2a, k2b);
    uint32_t u0 = 0, u1 = 0;  threefry2x32_host(k2a, k2b, u0, u1);
    uint32_t v0 = 0, v1 = 1;  threefry2x32_host(k2a, k2b, v0, v1);
    int far0 = (int)((u0 ^ u1) & (NPTS - 1));
    int far1 = (int)((v0 ^ v1) & (NPTS - 1));

    hipLaunchKernelGGL(fps_kernel, dim3(NB), dim3(T1), 0, stream,
                       xyz, new_xyz, far0, far1);
    hipLaunchKernelGGL(group_mlp_kernel, dim3(NB * SOUT), dim3(T2), 0, stream,
                       xyz, points, w1, b1, w2, b2, w3, b3, new_xyz, new_points);
}